// Round 9
// baseline (337.073 us; speedup 1.0000x reference)
//
#include <hip/hip_runtime.h>

// Problem constants (fixed by the reference)
#define B_   2
#define DZ   41
#define HY   400
#define WX   352
#define NVOX 40000
#define PD   43      // DZ+2
#define PH   402     // HY+2
#define PW   354     // WX+2
#define DO_  21
#define HO_  200
#define WO_  176
#define C1   128
#define GRID_CELLS (B_*PD*PH*PW)        // 12,238,488 cells (uint16)
#define OUT_POS    (B_*DO_*HO_*WO_)     // 1,478,400

// MODEL (fits R3-R8): dur_us includes ~240us of fixed harness stream ops per
// replay (0xAA poison fills measured 110-114us each, >=2/replay, plus input
// restore). Our controllable slice ~65us: memset-out 29 (irreducible 189MB),
// memset-grid 4, front ~15, scatter+relu ~15. R4 (this exact config) = 304.5
// best; R6 dense writer / R7 dedup gather / R8 fused-nbr front all regressed.
// This round: verbatim R4 resubmission (reproduction check + revert-to-best).

// ---- build padded dense grid of (voxel id + 1), 0 = empty ----
__global__ void k_build(const int* __restrict__ coors, unsigned short* __restrict__ grid) {
    int n = blockIdx.x * blockDim.x + threadIdx.x;
    if (n >= NVOX) return;
    int b = coors[4*n+0], z = coors[4*n+1], y = coors[4*n+2], x = coors[4*n+3];
    grid[((b*PD + z+1)*PH + y+1)*PW + x+1] = (unsigned short)(n + 1);
}

// ---- compact neighbor list per voxel: nbrc[n*28] = [cnt, (k<<16|idx)...] ----
__global__ void k_nbrc(const int* __restrict__ coors, const unsigned short* __restrict__ grid,
                       int* __restrict__ nbrc) {
    int n = blockIdx.x * 256 + threadIdx.x;
    if (n >= NVOX) return;
    int b = coors[4*n+0], z = coors[4*n+1], y = coors[4*n+2], x = coors[4*n+3];
    int* dst = nbrc + n * 28;
    int cnt = 0;
    for (int k = 0; k < 27; ++k) {
        int dz = k / 9, dy = (k / 3) % 3, dx = k % 3;
        int id = (int)grid[((b*PD + z+dz)*PH + y+dy)*PW + x+dx] - 1;
        if (id >= 0) dst[1 + cnt++] = (k << 16) | id;
    }
    dst[0] = cnt;
}

// ---- subm conv 1: 128 -> 16, ReLU. block = 16 voxels x 16 d ----
__global__ void k_subm1(const float* __restrict__ feat,
                        const float* __restrict__ W1,
                        const int* __restrict__ nbrc, float* __restrict__ x1) {
    __shared__ int s_p[16][28];
    int base = blockIdx.x * 16;
    for (int i = threadIdx.x; i < 16*28; i += 256) {
        int v = i / 28, j = i % 28;
        int n = base + v;
        s_p[v][j] = (n < NVOX) ? nbrc[n*28 + j] : 0;
    }
    __syncthreads();
    int v = threadIdx.x >> 4, d = threadIdx.x & 15;
    int n = base + v;
    if (n >= NVOX) return;
    int cnt = s_p[v][0];
    float acc = 0.f;
    for (int t = 1; t <= cnt; ++t) {
        int pk = s_p[v][t];
        int k = pk >> 16, idx = pk & 0xFFFF;
        const float4* f4 = (const float4*)(feat + (size_t)idx * C1);
        const float* w = W1 + k * (C1*16) + d;
        #pragma unroll 8
        for (int c4 = 0; c4 < 32; ++c4) {
            float4 f = f4[c4];
            acc += f.x * w[(c4*4+0)*16];
            acc += f.y * w[(c4*4+1)*16];
            acc += f.z * w[(c4*4+2)*16];
            acc += f.w * w[(c4*4+3)*16];
        }
    }
    x1[n*16 + d] = fmaxf(acc, 0.f);
}

// ---- subm conv 2: 16 -> 16, ReLU. block = 16 voxels x 16 d ----
__global__ void k_subm2(const float* __restrict__ x1,
                        const float* __restrict__ W2,
                        const int* __restrict__ nbrc, float* __restrict__ x2) {
    __shared__ int s_p[16][28];
    int base = blockIdx.x * 16;
    for (int i = threadIdx.x; i < 16*28; i += 256) {
        int v = i / 28, j = i % 28;
        int n = base + v;
        s_p[v][j] = (n < NVOX) ? nbrc[n*28 + j] : 0;
    }
    __syncthreads();
    int v = threadIdx.x >> 4, d = threadIdx.x & 15;
    int n = base + v;
    if (n >= NVOX) return;
    int cnt = s_p[v][0];
    float acc = 0.f;
    for (int t = 1; t <= cnt; ++t) {
        int pk = s_p[v][t];
        int k = pk >> 16, idx = pk & 0xFFFF;
        const float4* xr = (const float4*)(x1 + (size_t)idx * 16);
        float4 a0 = xr[0], a1 = xr[1], a2 = xr[2], a3 = xr[3];
        const float* w = W2 + k * 256 + d;
        acc += a0.x*w[0*16]  + a0.y*w[1*16]  + a0.z*w[2*16]  + a0.w*w[3*16]
             + a1.x*w[4*16]  + a1.y*w[5*16]  + a1.z*w[6*16]  + a1.w*w[7*16]
             + a2.x*w[8*16]  + a2.y*w[9*16]  + a2.z*w[10*16] + a2.w*w[11*16]
             + a3.x*w[12*16] + a3.y*w[13*16] + a3.z*w[14*16] + a3.w*w[15*16];
    }
    x2[n*16 + d] = fmaxf(acc, 0.f);
}

// ---- valid downsample taps for one axis, from PADDED input coord ----
// o = pcoord - doff (doff 0..2) valid iff o even and 0 <= o/2 < outdim.
__device__ __forceinline__ int axis_taps(int pcoord, int outdim, int* ds, int* ps) {
    if (pcoord & 1) { ds[0] = 1; ps[0] = pcoord >> 1; return 1; }
    int h = pcoord >> 1, nu = 0;
    if (h < outdim) { ds[nu] = 0; ps[nu] = h; nu++; }
    ds[nu] = 2; ps[nu] = h - 1; nu++;
    return nu;
}

// ---- stride-2 conv 16 -> 32 as scatter: block = 8 voxels x 32 channels ----
__global__ void k_scatter(const float* __restrict__ x2,
                          const float* __restrict__ W3,
                          const int* __restrict__ coors,
                          float* __restrict__ out) {
    int v = threadIdx.x >> 5, d = threadIdx.x & 31;
    int n = blockIdx.x * 8 + v;
    if (n >= NVOX) return;
    int b  = coors[4*n+0];
    int zp = coors[4*n+1] + 1, yp = coors[4*n+2] + 1, xp = coors[4*n+3] + 1;
    int dz[2], pz[2], dy[2], py[2], dx[2], px[2];
    int nz = axis_taps(zp, DO_, dz, pz);
    int ny = axis_taps(yp, HO_, dy, py);
    int nx = axis_taps(xp, WO_, dx, px);
    const float4* xr = (const float4*)(x2 + (size_t)n * 16);
    float r[16];
    *(float4*)(r + 0)  = xr[0];
    *(float4*)(r + 4)  = xr[1];
    *(float4*)(r + 8)  = xr[2];
    *(float4*)(r + 12) = xr[3];
    int bofs = b * (DO_*HO_*WO_);
    for (int iz = 0; iz < nz; ++iz)
        for (int iy = 0; iy < ny; ++iy)
            for (int ix = 0; ix < nx; ++ix) {
                int k = dz[iz]*9 + dy[iy]*3 + dx[ix];
                int p = bofs + (pz[iz]*HO_ + py[iy])*WO_ + px[ix];
                const float* w = W3 + k*512 + d;   // W3[k][c][d], stride 32 over c
                float acc = 0.f;
                #pragma unroll
                for (int c = 0; c < 16; ++c) acc += r[c] * w[c * 32];
                atomicAdd(out + (size_t)p * 32 + d, acc);
            }
}

// ---- idempotent ReLU over touched positions ----
__global__ void k_relu(const int* __restrict__ coors, float* __restrict__ out) {
    int v = threadIdx.x >> 5, d = threadIdx.x & 31;
    int n = blockIdx.x * 8 + v;
    if (n >= NVOX) return;
    int b  = coors[4*n+0];
    int zp = coors[4*n+1] + 1, yp = coors[4*n+2] + 1, xp = coors[4*n+3] + 1;
    int dz[2], pz[2], dy[2], py[2], dx[2], px[2];
    int nz = axis_taps(zp, DO_, dz, pz);
    int ny = axis_taps(yp, HO_, dy, py);
    int nx = axis_taps(xp, WO_, dx, px);
    int bofs = b * (DO_*HO_*WO_);
    for (int iz = 0; iz < nz; ++iz)
        for (int iy = 0; iy < ny; ++iy)
            for (int ix = 0; ix < nx; ++ix) {
                int p = bofs + (pz[iz]*HO_ + py[iy])*WO_ + px[ix];
                size_t o = (size_t)p * 32 + d;
                out[o] = fmaxf(out[o], 0.f);
            }
}

extern "C" void kernel_launch(void* const* d_in, const int* in_sizes, int n_in,
                              void* d_out, int out_size, void* d_ws, size_t ws_size,
                              hipStream_t stream) {
    const float* feat  = (const float*)d_in[0];  // f32 (N,128)
    const int*   coors = (const int*)d_in[1];    // int32 (N,4)
    const float* W1    = (const float*)d_in[2];  // f32 (27,128,16)
    const float* W2    = (const float*)d_in[3];  // f32 (27,16,16)
    const float* W3    = (const float*)d_in[4];  // f32 (27,16,32)
    float* out = (float*)d_out;                  // f32 (2,21,200,176,32)

    char* ws = (char*)d_ws;
    size_t off = 0;
    unsigned short* grid = (unsigned short*)(ws + off);
    off += (((size_t)GRID_CELLS*2) + 255) & ~(size_t)255;
    int* nbrc = (int*)(ws + off); off += (((size_t)NVOX*28*4)  + 255) & ~(size_t)255;
    float* x1 = (float*)(ws + off); off += (((size_t)NVOX*16*4) + 255) & ~(size_t)255;
    float* x2 = (float*)(ws + off);

    hipMemsetAsync(grid, 0x00, (size_t)GRID_CELLS * 2, stream);     // grid = 0 (empty)
    hipMemsetAsync(out, 0x00, (size_t)OUT_POS * 32 * sizeof(float), stream);
    k_build<<<(NVOX + 255) / 256, 256, 0, stream>>>(coors, grid);
    k_nbrc<<<(NVOX + 255) / 256, 256, 0, stream>>>(coors, grid, nbrc);
    k_subm1<<<(NVOX + 15) / 16, 256, 0, stream>>>(feat, W1, nbrc, x1);
    k_subm2<<<(NVOX + 15) / 16, 256, 0, stream>>>(x1, W2, nbrc, x2);
    k_scatter<<<(NVOX + 7) / 8, 256, 0, stream>>>(x2, W3, coors, out);
    k_relu<<<(NVOX + 7) / 8, 256, 0, stream>>>(coors, out);
}